// Round 1
// baseline (1282.400 us; speedup 1.0000x reference)
//
#include <hip/hip_runtime.h>

static constexpr int Lp = 128;
static constexpr int Dp = 768;
static constexpr int Bp = 8;
static constexpr int CELLS = Bp * Lp * Lp;   // 131072
static constexpr int LL = Lp * Lp;           // 16384

__device__ __forceinline__ float dot4(float4 a, float4 w) {
    return a.x * w.x + a.y * w.y + a.z * w.z + a.w * w.w;
}

// One wave (64 lanes) per (b,m,n) cell, grid-stride. Lane l loads float4
// indices {l, l+64, l+128} of the cell's 192 float4s (coalesced 16B/lane).
__global__ __launch_bounds__(256) void logits_loss_kernel(
    const float* __restrict__ table,
    const int* __restrict__ labS,
    const int* __restrict__ labE,
    const float* __restrict__ WS, const float* __restrict__ bSp,
    const float* __restrict__ WE, const float* __restrict__ bEp,
    float* __restrict__ out)   // [0]=loss_S [1]=loss_E [2..]=predS [2+CELLS..]=predE
{
    const int lane  = threadIdx.x & 63;
    const int gwave = (int)((blockIdx.x * blockDim.x + threadIdx.x) >> 6);
    const int nwaves = (int)((gridDim.x * blockDim.x) >> 6);

    // Per-lane W fragments, loaded once and reused across all cells.
    const float4* wS4 = (const float4*)WS;
    const float4* wE4 = (const float4*)WE;
    const float4 ws0 = wS4[lane], ws1 = wS4[lane + 64], ws2 = wS4[lane + 128];
    const float4 we0 = wE4[lane], we1 = wE4[lane + 64], we2 = wE4[lane + 128];
    const float bs = bSp[0], be = bEp[0];

    float* __restrict__ predS = out + 2;
    float* __restrict__ predE = out + 2 + CELLS;

    float accS = 0.f, accE = 0.f;

    for (int c = gwave; c < CELLS; c += nwaves) {
        const float4* t4 = (const float4*)(table + (size_t)c * Dp);
        float4 x0 = t4[lane];
        float4 x1 = t4[lane + 64];
        float4 x2 = t4[lane + 128];
        float s = dot4(x0, ws0) + dot4(x1, ws1) + dot4(x2, ws2);
        float e = dot4(x0, we0) + dot4(x1, we1) + dot4(x2, we2);
        #pragma unroll
        for (int off = 32; off; off >>= 1) {
            s += __shfl_down(s, off);
            e += __shfl_down(e, off);
        }
        if (lane == 0) {
            float xS = s + bs;
            float xE = e + be;
            int lS = labS[c];
            int lE = labE[c];
            float w  = (lS >= 0) ? 1.0f : 0.0f;   // weight from labels_S for BOTH
            float tS = (float)lS;
            float tE = (float)lE;
            // stable BCE-with-logits: logaddexp(0,x) - x*t
            float bceS = fmaxf(xS, 0.f) + log1pf(expf(-fabsf(xS))) - xS * tS;
            float bceE = fmaxf(xE, 0.f) + log1pf(expf(-fabsf(xE))) - xE * tE;
            accS += w * bceS;
            accE += w * bceE;
            predS[c] = w / (1.f + expf(-xS));     // sigmoid * weight
            predE[c] = w / (1.f + expf(-xE));
        }
    }
    if (lane == 0) {
        const float inv = 1.0f / (float)CELLS;
        atomicAdd(out + 0, accS * inv);
        atomicAdd(out + 1, accE * inv);
    }
}

// One block per (head, batch): exact k-th-largest via binary search on the
// uint bit pattern (valid: all preds are non-negative floats), then write
// predict = (pred >= kth) as 0/1 floats in place.
__global__ __launch_bounds__(1024) void topk_predict_kernel(
    const int* __restrict__ attn, float* __restrict__ out)
{
    const int b    = blockIdx.x & 7;
    const int head = blockIdx.x >> 3;
    float* arr = out + 2 + head * CELLS + b * LL;
    const int tid = threadIdx.x;

    __shared__ int sh_ml;
    __shared__ int sh_k;
    __shared__ unsigned sh_total;

    if (tid == 0) sh_ml = 0;
    __syncthreads();
    if (tid < Lp) atomicAdd(&sh_ml, attn[b * Lp + tid]);
    __syncthreads();
    if (tid == 0) {
        int ml  = sh_ml - 2;
        int len = (int)((float)ml * 0.3f);   // trunc, like .astype(int32)
        len = len > 5 ? len : 5;
        int cap = ml * ml;
        len = len < cap ? len : cap;
        sh_k = len;
    }
    __syncthreads();
    const unsigned k = (unsigned)sh_k;

    unsigned v[16];
    #pragma unroll
    for (int i = 0; i < 16; i++)
        v[i] = __float_as_uint(arr[tid + i * 1024]);

    unsigned lo = 0u, hi = 0x3F800001u;   // covers [0.0, 1.0] inclusive
    while (hi - lo > 1u) {
        unsigned mid = lo + ((hi - lo) >> 1);
        if (tid == 0) sh_total = 0u;
        __syncthreads();
        int cnt = 0;
        #pragma unroll
        for (int i = 0; i < 16; i++) cnt += (v[i] >= mid) ? 1 : 0;
        #pragma unroll
        for (int off = 32; off; off >>= 1) cnt += __shfl_down(cnt, off);
        if ((tid & 63) == 0) atomicAdd(&sh_total, (unsigned)cnt);
        __syncthreads();
        unsigned total = sh_total;
        if (total >= k) lo = mid; else hi = mid;
        __syncthreads();
    }

    #pragma unroll
    for (int i = 0; i < 16; i++)
        arr[tid + i * 1024] = (v[i] >= lo) ? 1.0f : 0.0f;
}

extern "C" void kernel_launch(void* const* d_in, const int* in_sizes, int n_in,
                              void* d_out, int out_size, void* d_ws, size_t ws_size,
                              hipStream_t stream) {
    const float* table = (const float*)d_in[0];
    const int*   attn  = (const int*)d_in[1];
    const int*   labS  = (const int*)d_in[2];
    const int*   labE  = (const int*)d_in[3];
    const float* WS    = (const float*)d_in[4];
    const float* bS    = (const float*)d_in[5];
    const float* WE    = (const float*)d_in[6];
    const float* bE    = (const float*)d_in[7];
    float* out = (float*)d_out;

    // d_out is re-poisoned before every timed launch: zero the loss accumulators.
    hipMemsetAsync(out, 0, 2 * sizeof(float), stream);

    // 8192 blocks x 4 waves = 32768 waves; 131072 cells -> 4 cells/wave.
    logits_loss_kernel<<<8192, 256, 0, stream>>>(table, labS, labE, WS, bS, WE, bE, out);
    topk_predict_kernel<<<16, 1024, 0, stream>>>(attn, out);
}

// Round 2
// 625.073 us; speedup vs baseline: 2.0516x; 2.0516x over previous
//
#include <hip/hip_runtime.h>

static constexpr int Lp = 128;
static constexpr int Dp = 768;
static constexpr int Bp = 8;
static constexpr int CELLS = Bp * Lp * Lp;   // 131072
static constexpr int LL = Lp * Lp;           // 16384
static constexpr int BLOCKS = 2048;          // logits kernel blocks
static constexpr int CPW = 16;               // cells per wave (2048*4*16 == CELLS)

__device__ __forceinline__ float dot4(float4 a, float4 w) {
    return a.x * w.x + a.y * w.y + a.z * w.z + a.w * w.w;
}

// 2048 blocks x 256 threads (4 waves). Each wave handles 16 consecutive cells,
// unrolled x2 so two cells' loads + reduce chains overlap. Loss goes to
// per-block partials in d_ws (no global same-address atomics at all).
__global__ __launch_bounds__(256) void logits_loss_kernel(
    const float* __restrict__ table,
    const int* __restrict__ labS,
    const int* __restrict__ labE,
    const float* __restrict__ WS, const float* __restrict__ bSp,
    const float* __restrict__ WE, const float* __restrict__ bEp,
    float* __restrict__ out,          // [0..1] losses (written later), [2..] preds
    float2* __restrict__ partial)     // [BLOCKS] per-block loss partials
{
    const int lane = threadIdx.x & 63;
    const int wid  = threadIdx.x >> 6;               // wave in block (0..3)
    const int gwave = blockIdx.x * 4 + wid;
    const int c0 = gwave * CPW;

    // Per-lane W fragments (24 VGPR), reused for all cells.
    const float4* wS4 = (const float4*)WS;
    const float4* wE4 = (const float4*)WE;
    const float4 ws0 = wS4[lane], ws1 = wS4[lane + 64], ws2 = wS4[lane + 128];
    const float4 we0 = wE4[lane], we1 = wE4[lane + 64], we2 = wE4[lane + 128];
    const float bs = bSp[0], be = bEp[0];

    // Coalesced label preload: lanes 0..15 hold labels for the wave's 16 cells.
    int myLS = 0, myLE = 0;
    if (lane < CPW) { myLS = labS[c0 + lane]; myLE = labE[c0 + lane]; }

    float* __restrict__ predS = out + 2;
    float* __restrict__ predE = out + 2 + CELLS;

    float accS = 0.f, accE = 0.f;
    const float4* t4 = (const float4*)table + (size_t)c0 * 192;

    #pragma unroll 2
    for (int i = 0; i < CPW; i += 2) {
        const float4* p = t4 + (size_t)i * 192;
        // cell i
        float4 a0 = p[lane], a1 = p[lane + 64], a2 = p[lane + 128];
        // cell i+1
        float4 q0 = p[lane + 192], q1 = p[lane + 256], q2 = p[lane + 320];

        float s0 = dot4(a0, ws0) + dot4(a1, ws1) + dot4(a2, ws2);
        float e0 = dot4(a0, we0) + dot4(a1, we1) + dot4(a2, we2);
        float s1 = dot4(q0, ws0) + dot4(q1, ws1) + dot4(q2, ws2);
        float e1 = dot4(q0, we0) + dot4(q1, we1) + dot4(q2, we2);

        #pragma unroll
        for (int off = 32; off; off >>= 1) {   // 4 independent chains overlap
            s0 += __shfl_down(s0, off);
            e0 += __shfl_down(e0, off);
            s1 += __shfl_down(s1, off);
            e1 += __shfl_down(e1, off);
        }

        // labels for cells i, i+1 (all lanes execute the shfl)
        int lSa = __shfl(myLS, i),     lEa = __shfl(myLE, i);
        int lSb = __shfl(myLS, i + 1), lEb = __shfl(myLE, i + 1);

        if (lane == 0) {
            float xS = s0 + bs, xE = e0 + be;
            float w  = (lSa >= 0) ? 1.0f : 0.0f;
            accS += w * (fmaxf(xS, 0.f) + log1pf(expf(-fabsf(xS))) - xS * (float)lSa);
            accE += w * (fmaxf(xE, 0.f) + log1pf(expf(-fabsf(xE))) - xE * (float)lEa);
            predS[c0 + i] = w / (1.f + expf(-xS));
            predE[c0 + i] = w / (1.f + expf(-xE));

            float xS2 = s1 + bs, xE2 = e1 + be;
            float w2  = (lSb >= 0) ? 1.0f : 0.0f;
            accS += w2 * (fmaxf(xS2, 0.f) + log1pf(expf(-fabsf(xS2))) - xS2 * (float)lSb);
            accE += w2 * (fmaxf(xE2, 0.f) + log1pf(expf(-fabsf(xE2))) - xE2 * (float)lEb);
            predS[c0 + i + 1] = w2 / (1.f + expf(-xS2));
            predE[c0 + i + 1] = w2 / (1.f + expf(-xE2));
        }
    }

    __shared__ float redS[4], redE[4];
    if (lane == 0) { redS[wid] = accS; redE[wid] = accE; }
    __syncthreads();
    if (threadIdx.x == 0) {
        float2 pr;
        pr.x = redS[0] + redS[1] + redS[2] + redS[3];
        pr.y = redE[0] + redE[1] + redE[2] + redE[3];
        partial[blockIdx.x] = pr;
    }
}

// One small block sums the 2048 per-block partials and writes the two losses.
__global__ __launch_bounds__(256) void loss_reduce_kernel(
    const float2* __restrict__ partial, float* __restrict__ out)
{
    const int tid = threadIdx.x;
    float s = 0.f, e = 0.f;
    for (int i = tid; i < BLOCKS; i += 256) {
        float2 p = partial[i];
        s += p.x; e += p.y;
    }
    #pragma unroll
    for (int off = 32; off; off >>= 1) {
        s += __shfl_down(s, off);
        e += __shfl_down(e, off);
    }
    __shared__ float shS[4], shE[4];
    if ((tid & 63) == 0) { shS[tid >> 6] = s; shE[tid >> 6] = e; }
    __syncthreads();
    if (tid == 0) {
        const float inv = 1.0f / (float)CELLS;
        out[0] = (shS[0] + shS[1] + shS[2] + shS[3]) * inv;
        out[1] = (shE[0] + shE[1] + shE[2] + shE[3]) * inv;
    }
}

// One block per (head, batch): exact k-th-largest via 4-round radix select
// (8 bits/round) on the uint bit pattern (preds >= 0 so uint order = float
// order), then write predict = (pred >= kth) as 0/1 floats in place.
__global__ __launch_bounds__(1024) void topk_predict_kernel(
    const int* __restrict__ attn, float* __restrict__ out)
{
    const int b    = blockIdx.x & 7;
    const int head = blockIdx.x >> 3;
    float* arr = out + 2 + head * CELLS + b * LL;
    const int tid = threadIdx.x;

    __shared__ unsigned hist[256];
    __shared__ int sh_ml;
    __shared__ unsigned sh_kk;
    __shared__ unsigned sh_prefix;

    if (tid == 0) sh_ml = 0;
    __syncthreads();
    if (tid < Lp) atomicAdd(&sh_ml, attn[b * Lp + tid]);
    __syncthreads();
    if (tid == 0) {
        int ml  = sh_ml - 2;
        int len = (int)((float)ml * 0.3f);   // f32 trunc, like reference
        len = len > 5 ? len : 5;
        int cap = ml * ml;
        len = len < cap ? len : cap;
        sh_kk = (unsigned)len;
        sh_prefix = 0u;
    }
    __syncthreads();

    unsigned v[16];
    #pragma unroll
    for (int i = 0; i < 16; i++)
        v[i] = __float_as_uint(arr[tid + i * 1024]);

    #pragma unroll
    for (int shift = 24; shift >= 0; shift -= 8) {
        if (tid < 256) hist[tid] = 0u;
        __syncthreads();
        const unsigned prefix = sh_prefix;
        const unsigned hmask = (shift == 24) ? 0u : (0xFFFFFFFFu << (shift + 8));
        #pragma unroll
        for (int i = 0; i < 16; i++) {
            if ((v[i] & hmask) == (prefix & hmask))
                atomicAdd(&hist[(v[i] >> shift) & 255u], 1u);
        }
        __syncthreads();
        if (tid == 0) {
            unsigned kk = sh_kk, acc = 0u;
            int bsel = 0;
            for (int bin = 255; bin >= 0; bin--) {
                unsigned c = hist[bin];
                if (acc + c >= kk) { bsel = bin; sh_kk = kk - acc; break; }
                acc += c;
            }
            sh_prefix = prefix | ((unsigned)bsel << shift);
        }
        __syncthreads();
    }

    const unsigned kth = sh_prefix;   // exact k-th largest key
    #pragma unroll
    for (int i = 0; i < 16; i++)
        arr[tid + i * 1024] = (v[i] >= kth) ? 1.0f : 0.0f;
}

extern "C" void kernel_launch(void* const* d_in, const int* in_sizes, int n_in,
                              void* d_out, int out_size, void* d_ws, size_t ws_size,
                              hipStream_t stream) {
    const float* table = (const float*)d_in[0];
    const int*   attn  = (const int*)d_in[1];
    const int*   labS  = (const int*)d_in[2];
    const int*   labE  = (const int*)d_in[3];
    const float* WS    = (const float*)d_in[4];
    const float* bS    = (const float*)d_in[5];
    const float* WE    = (const float*)d_in[6];
    const float* bE    = (const float*)d_in[7];
    float* out = (float*)d_out;
    float2* partial = (float2*)d_ws;   // 2048 float2 = 16 KB

    logits_loss_kernel<<<BLOCKS, 256, 0, stream>>>(table, labS, labE, WS, bS, WE, bE,
                                                   out, partial);
    loss_reduce_kernel<<<1, 256, 0, stream>>>(partial, out);
    topk_predict_kernel<<<16, 1024, 0, stream>>>(attn, out);
}

// Round 3
// 555.992 us; speedup vs baseline: 2.3065x; 1.1242x over previous
//
#include <hip/hip_runtime.h>

static constexpr int Lp = 128;
static constexpr int Dp = 768;
static constexpr int Bp = 8;
static constexpr int CELLS = Bp * Lp * Lp;   // 131072
static constexpr int LL = Lp * Lp;           // 16384
static constexpr int BLOCKS = 4096;          // logits kernel blocks
static constexpr int CPW = 8;                // cells per wave (4096*4*8 == CELLS)

__device__ __forceinline__ float dot4(float4 a, float4 w) {
    return a.x * w.x + a.y * w.y + a.z * w.z + a.w * w.w;
}

__device__ __forceinline__ void cell_epilogue(
    float s, float e, int lS, int lE, float bs, float be,
    float& accS, float& accE, float* pS, float* pE)
{
    float xS = s + bs, xE = e + be;
    float w = (lS >= 0) ? 1.0f : 0.0f;
    float eS = expf(-fabsf(xS));               // shared by BCE and sigmoid
    float eE = expf(-fabsf(xE));
    accS += w * (fmaxf(xS, 0.f) + log1pf(eS) - xS * (float)lS);
    accE += w * (fmaxf(xE, 0.f) + log1pf(eE) - xE * (float)lE);
    *pS = w * ((xS >= 0.f ? 1.f : eS) / (1.f + eS));
    *pE = w * ((xE >= 0.f ? 1.f : eE) / (1.f + eE));
}

// 4096 blocks x 256 threads. Each wave: 8 cells, processed 4 at a time with
// all 12 float4 loads issued before any use (launch_bounds(256,4) -> VGPR cap
// 128 so the compiler can keep them all in flight). Losses -> per-block
// partials in d_ws.
__global__ __launch_bounds__(256, 4) void logits_loss_kernel(
    const float* __restrict__ table,
    const int* __restrict__ labS,
    const int* __restrict__ labE,
    const float* __restrict__ WS, const float* __restrict__ bSp,
    const float* __restrict__ WE, const float* __restrict__ bEp,
    float* __restrict__ out,
    float2* __restrict__ partial)
{
    const int lane = threadIdx.x & 63;
    const int wid  = threadIdx.x >> 6;
    const int gwave = blockIdx.x * 4 + wid;
    const int cell0 = gwave * CPW;

    const float4* wS4 = (const float4*)WS;
    const float4* wE4 = (const float4*)WE;
    const float4 ws0 = wS4[lane], ws1 = wS4[lane + 64], ws2 = wS4[lane + 128];
    const float4 we0 = wE4[lane], we1 = wE4[lane + 64], we2 = wE4[lane + 128];
    const float bs = bSp[0], be = bEp[0];

    int myLS = 0, myLE = 0;
    if (lane < CPW) { myLS = labS[cell0 + lane]; myLE = labE[cell0 + lane]; }

    float* __restrict__ predS = out + 2;
    float* __restrict__ predE = out + 2 + CELLS;

    float accS = 0.f, accE = 0.f;
    const float4* t4 = (const float4*)table + (size_t)cell0 * 192;

    for (int i = 0; i < CPW; i += 4) {
        const float4* p = t4 + (size_t)i * 192;
        // 12 independent coalesced loads, all issued before any consumption
        float4 a0 = p[lane      ], a1 = p[lane +  64], a2 = p[lane + 128];
        float4 b0 = p[lane + 192], b1 = p[lane + 256], b2 = p[lane + 320];
        float4 g0 = p[lane + 384], g1 = p[lane + 448], g2 = p[lane + 512];
        float4 d0 = p[lane + 576], d1 = p[lane + 640], d2 = p[lane + 704];

        float s0 = dot4(a0, ws0) + dot4(a1, ws1) + dot4(a2, ws2);
        float e0 = dot4(a0, we0) + dot4(a1, we1) + dot4(a2, we2);
        float s1 = dot4(b0, ws0) + dot4(b1, ws1) + dot4(b2, ws2);
        float e1 = dot4(b0, we0) + dot4(b1, we1) + dot4(b2, we2);
        float s2 = dot4(g0, ws0) + dot4(g1, ws1) + dot4(g2, ws2);
        float e2 = dot4(g0, we0) + dot4(g1, we1) + dot4(g2, we2);
        float s3 = dot4(d0, ws0) + dot4(d1, ws1) + dot4(d2, ws2);
        float e3 = dot4(d0, we0) + dot4(d1, we1) + dot4(d2, we2);

        #pragma unroll
        for (int off = 32; off; off >>= 1) {   // 8 independent chains
            s0 += __shfl_down(s0, off); e0 += __shfl_down(e0, off);
            s1 += __shfl_down(s1, off); e1 += __shfl_down(e1, off);
            s2 += __shfl_down(s2, off); e2 += __shfl_down(e2, off);
            s3 += __shfl_down(s3, off); e3 += __shfl_down(e3, off);
        }

        int lS0 = __shfl(myLS, i    ), lE0 = __shfl(myLE, i    );
        int lS1 = __shfl(myLS, i + 1), lE1 = __shfl(myLE, i + 1);
        int lS2 = __shfl(myLS, i + 2), lE2 = __shfl(myLE, i + 2);
        int lS3 = __shfl(myLS, i + 3), lE3 = __shfl(myLE, i + 3);

        if (lane == 0) {
            int c = cell0 + i;
            cell_epilogue(s0, e0, lS0, lE0, bs, be, accS, accE, predS + c,     predE + c);
            cell_epilogue(s1, e1, lS1, lE1, bs, be, accS, accE, predS + c + 1, predE + c + 1);
            cell_epilogue(s2, e2, lS2, lE2, bs, be, accS, accE, predS + c + 2, predE + c + 2);
            cell_epilogue(s3, e3, lS3, lE3, bs, be, accS, accE, predS + c + 3, predE + c + 3);
        }
    }

    __shared__ float redS[4], redE[4];
    if (lane == 0) { redS[wid] = accS; redE[wid] = accE; }
    __syncthreads();
    if (threadIdx.x == 0) {
        float2 pr;
        pr.x = redS[0] + redS[1] + redS[2] + redS[3];
        pr.y = redE[0] + redE[1] + redE[2] + redE[3];
        partial[blockIdx.x] = pr;
    }
}

__global__ __launch_bounds__(256) void loss_reduce_kernel(
    const float2* __restrict__ partial, float* __restrict__ out)
{
    const int tid = threadIdx.x;
    float s = 0.f, e = 0.f;
    for (int i = tid; i < BLOCKS; i += 256) {
        float2 p = partial[i];
        s += p.x; e += p.y;
    }
    #pragma unroll
    for (int off = 32; off; off >>= 1) {
        s += __shfl_down(s, off);
        e += __shfl_down(e, off);
    }
    __shared__ float shS[4], shE[4];
    if ((tid & 63) == 0) { shS[tid >> 6] = s; shE[tid >> 6] = e; }
    __syncthreads();
    if (tid == 0) {
        const float inv = 1.0f / (float)CELLS;
        out[0] = (shS[0] + shS[1] + shS[2] + shS[3]) * inv;
        out[1] = (shE[0] + shE[1] + shE[2] + shE[3]) * inv;
    }
}

// One block per (head, batch). Exact k-th largest via value-space bucketing
// (floor(v*256): monotone; sigmoid outputs spread nearly uniformly in value
// space, unlike float bit patterns), wave-parallel suffix scan, candidate
// compaction, and strict-greater counting for the exact float threshold.
__global__ __launch_bounds__(1024) void topk_predict_kernel(
    const int* __restrict__ attn, float* __restrict__ out)
{
    const int b    = blockIdx.x & 7;
    const int head = blockIdx.x >> 3;
    float* arr = out + 2 + head * CELLS + b * LL;
    const int tid = threadIdx.x;

    __shared__ unsigned hist[256];
    __shared__ unsigned cand[4096];
    __shared__ unsigned sh_B, sh_kk, sh_thr, sh_ccnt;

    if (tid < 256) hist[tid] = 0u;
    if (tid == 0) { sh_ccnt = 0u; sh_thr = 0x7F800000u; }
    __syncthreads();

    unsigned vu[16];
    int bk[16];
    #pragma unroll
    for (int i = 0; i < 16; i++) {
        float f = arr[tid + i * 1024];
        vu[i] = __float_as_uint(f);
        int bb = (int)(f * 256.0f);
        bk[i] = bb > 255 ? 255 : bb;
        atomicAdd(&hist[bk[i]], 1u);
    }
    __syncthreads();

    if (tid < 64) {
        const int lane = tid;
        // k from the attention mask (wave reduce, no atomics)
        int m = attn[b * Lp + lane] + attn[b * Lp + 64 + lane];
        #pragma unroll
        for (int off = 32; off; off >>= 1) m += __shfl_down(m, off);
        m = __shfl(m, 0);
        int ml  = m - 2;
        int len = (int)((float)ml * 0.3f);
        len = len > 5 ? len : 5;
        int cap = ml * ml;
        len = len < cap ? len : cap;
        const unsigned k = (unsigned)len;

        // lane owns bins 4*lane .. 4*lane+3; suffix-scan across lanes via shfl
        unsigned h0 = hist[4 * lane], h1 = hist[4 * lane + 1];
        unsigned h2 = hist[4 * lane + 2], h3 = hist[4 * lane + 3];
        unsigned s = h0 + h1 + h2 + h3;
        unsigned suf = s;
        #pragma unroll
        for (int off = 1; off < 64; off <<= 1) {
            unsigned t = __shfl_down(suf, off);
            if (lane + off < 64) suf += t;
        }
        unsigned above = suf - s;              // total in bins > 4*lane+3
        unsigned suf3 = above + h3;            // suffix[4l+3]
        unsigned suf2 = suf3 + h2;             // suffix[4l+2]
        unsigned suf1 = suf2 + h1;
        unsigned suf0 = suf1 + h0;
        // max bin j with suffix[j] >= k, plus suffix[j+1]
        int best = -1; unsigned snext = 0u;
        if      (suf3 >= k) { best = 4 * lane + 3; snext = above; }
        else if (suf2 >= k) { best = 4 * lane + 2; snext = suf3; }
        else if (suf1 >= k) { best = 4 * lane + 1; snext = suf2; }
        else if (suf0 >= k) { best = 4 * lane;     snext = suf1; }
        unsigned long long msk = __ballot(best != -1);
        int blane = 63 - __clzll(msk);         // highest lane with a qualifying bin
        if (lane == blane) { sh_B = (unsigned)best; sh_kk = k - snext; }
    }
    __syncthreads();

    const int B = (int)sh_B;
    const unsigned kk = sh_kk;

    #pragma unroll
    for (int i = 0; i < 16; i++) {
        if (bk[i] == B) {
            unsigned idx = atomicAdd(&sh_ccnt, 1u);
            if (idx < 4096u) cand[idx] = vu[i];
        }
    }
    __syncthreads();

    const unsigned C = sh_ccnt < 4096u ? sh_ccnt : 4096u;
    for (unsigned j = tid; j < C; j += 1024) {
        unsigned x = cand[j], g = 0u;
        for (unsigned i2 = 0; i2 < C; ++i2) g += (cand[i2] > x) ? 1u : 0u;
        if (g < kk) atomicMin(&sh_thr, x);     // min qualifying = exact k-th largest
    }
    __syncthreads();

    const unsigned thr = sh_thr;
    #pragma unroll
    for (int i = 0; i < 16; i++)
        arr[tid + i * 1024] = (vu[i] >= thr) ? 1.0f : 0.0f;
}

extern "C" void kernel_launch(void* const* d_in, const int* in_sizes, int n_in,
                              void* d_out, int out_size, void* d_ws, size_t ws_size,
                              hipStream_t stream) {
    const float* table = (const float*)d_in[0];
    const int*   attn  = (const int*)d_in[1];
    const int*   labS  = (const int*)d_in[2];
    const int*   labE  = (const int*)d_in[3];
    const float* WS    = (const float*)d_in[4];
    const float* bS    = (const float*)d_in[5];
    const float* WE    = (const float*)d_in[6];
    const float* bE    = (const float*)d_in[7];
    float* out = (float*)d_out;
    float2* partial = (float2*)d_ws;

    logits_loss_kernel<<<BLOCKS, 256, 0, stream>>>(table, labS, labE, WS, bS, WE, bE,
                                                   out, partial);
    loss_reduce_kernel<<<1, 256, 0, stream>>>(partial, out);
    topk_predict_kernel<<<16, 1024, 0, stream>>>(attn, out);
}

// Round 4
// 546.426 us; speedup vs baseline: 2.3469x; 1.0175x over previous
//
#include <hip/hip_runtime.h>

static constexpr int Lp = 128;
static constexpr int Dp = 768;
static constexpr int Bp = 8;
static constexpr int CELLS = Bp * Lp * Lp;   // 131072
static constexpr int LL = Lp * Lp;           // 16384
static constexpr int BLOCKS = 4096;          // logits kernel blocks
static constexpr int CPW = 8;                // cells per wave (4096*4*8 == CELLS)

__device__ __forceinline__ float dot4(float4 a, float4 w) {
    return a.x * w.x + a.y * w.y + a.z * w.z + a.w * w.w;
}

// 4096 blocks x 256 threads. Each wave: 8 cells, 4 at a time, 12 float4 loads
// in flight before any use. Butterfly reduce gives every lane the 8 totals;
// lanes 0..3 run the 4 cells' epilogues IN PARALLEL (transcendentals off the
// single-lane critical path) and issue one coalesced 4-dword pred store.
__global__ __launch_bounds__(256, 4) void logits_loss_kernel(
    const float* __restrict__ table,
    const int* __restrict__ labS,
    const int* __restrict__ labE,
    const float* __restrict__ WS, const float* __restrict__ bSp,
    const float* __restrict__ WE, const float* __restrict__ bEp,
    float* __restrict__ out,
    float2* __restrict__ partial)
{
    const int lane = threadIdx.x & 63;
    const int wid  = threadIdx.x >> 6;
    const int gwave = blockIdx.x * 4 + wid;
    const int cell0 = gwave * CPW;

    const float4* wS4 = (const float4*)WS;
    const float4* wE4 = (const float4*)WE;
    const float4 ws0 = wS4[lane], ws1 = wS4[lane + 64], ws2 = wS4[lane + 128];
    const float4 we0 = wE4[lane], we1 = wE4[lane + 64], we2 = wE4[lane + 128];
    const float bs = bSp[0], be = bEp[0];

    int myLS = 0, myLE = 0;
    if (lane < CPW) { myLS = labS[cell0 + lane]; myLE = labE[cell0 + lane]; }

    float* __restrict__ predS = out + 2;
    float* __restrict__ predE = out + 2 + CELLS;

    float accS = 0.f, accE = 0.f;
    const float4* t4 = (const float4*)table + (size_t)cell0 * 192;

    for (int i = 0; i < CPW; i += 4) {
        const float4* p = t4 + (size_t)i * 192;
        float4 a0 = p[lane      ], a1 = p[lane +  64], a2 = p[lane + 128];
        float4 b0 = p[lane + 192], b1 = p[lane + 256], b2 = p[lane + 320];
        float4 g0 = p[lane + 384], g1 = p[lane + 448], g2 = p[lane + 512];
        float4 d0 = p[lane + 576], d1 = p[lane + 640], d2 = p[lane + 704];

        float s0 = dot4(a0, ws0) + dot4(a1, ws1) + dot4(a2, ws2);
        float e0 = dot4(a0, we0) + dot4(a1, we1) + dot4(a2, we2);
        float s1 = dot4(b0, ws0) + dot4(b1, ws1) + dot4(b2, ws2);
        float e1 = dot4(b0, we0) + dot4(b1, we1) + dot4(b2, we2);
        float s2 = dot4(g0, ws0) + dot4(g1, ws1) + dot4(g2, ws2);
        float e2 = dot4(g0, we0) + dot4(g1, we1) + dot4(g2, we2);
        float s3 = dot4(d0, ws0) + dot4(d1, ws1) + dot4(d2, ws2);
        float e3 = dot4(d0, we0) + dot4(d1, we1) + dot4(d2, we2);

        #pragma unroll
        for (int off = 32; off; off >>= 1) {   // butterfly: all lanes get totals
            s0 += __shfl_xor(s0, off); e0 += __shfl_xor(e0, off);
            s1 += __shfl_xor(s1, off); e1 += __shfl_xor(e1, off);
            s2 += __shfl_xor(s2, off); e2 += __shfl_xor(e2, off);
            s3 += __shfl_xor(s3, off); e3 += __shfl_xor(e3, off);
        }

        const int sub = lane & 3;
        float s = sub == 0 ? s0 : sub == 1 ? s1 : sub == 2 ? s2 : s3;
        float e = sub == 0 ? e0 : sub == 1 ? e1 : sub == 2 ? e2 : e3;
        int lS = __shfl(myLS, i + sub);
        int lE = __shfl(myLE, i + sub);

        if (lane < 4) {
            const int c = cell0 + i + sub;
            float xS = s + bs, xE = e + be;
            float w = (lS >= 0) ? 1.0f : 0.0f;
            float eS = expf(-fabsf(xS));
            float eE = expf(-fabsf(xE));
            accS += w * (fmaxf(xS, 0.f) + log1pf(eS) - xS * (float)lS);
            accE += w * (fmaxf(xE, 0.f) + log1pf(eE) - xE * (float)lE);
            predS[c] = w * ((xS >= 0.f ? 1.f : eS) / (1.f + eS));   // coalesced quad
            predE[c] = w * ((xE >= 0.f ? 1.f : eE) / (1.f + eE));
        }
    }

    // acc lives only on lanes 0..3: two butterfly steps fold into lane 0
    accS += __shfl_xor(accS, 1); accE += __shfl_xor(accE, 1);
    accS += __shfl_xor(accS, 2); accE += __shfl_xor(accE, 2);

    __shared__ float redS[4], redE[4];
    if (lane == 0) { redS[wid] = accS; redE[wid] = accE; }
    __syncthreads();
    if (threadIdx.x == 0) {
        float2 pr;
        pr.x = redS[0] + redS[1] + redS[2] + redS[3];
        pr.y = redE[0] + redE[1] + redE[2] + redE[3];
        partial[blockIdx.x] = pr;
    }
}

// One block per (head, batch). 1024-bin value-space select; zeros counted via
// ballot (no same-address LDS atomic storm). Block 0 also folds in the loss
// reduction on its first 256 threads (saves a launch).
__global__ __launch_bounds__(1024) void topk_predict_kernel(
    const int* __restrict__ attn, float* __restrict__ out,
    const float2* __restrict__ partial)
{
    const int b    = blockIdx.x & 7;
    const int head = blockIdx.x >> 3;
    float* arr = out + 2 + head * CELLS + b * LL;
    const int tid = threadIdx.x;

    __shared__ unsigned hist[1024];
    __shared__ unsigned cand[2048];
    __shared__ unsigned sh_B, sh_kk, sh_thr, sh_ccnt;
    __shared__ float shS[4], shE[4];

    hist[tid] = 0u;
    if (tid == 0) { sh_ccnt = 0u; sh_thr = 0x7F800000u; }

    // fused loss reduce (block 0, waves 0..3 only; no barrier inside)
    if (blockIdx.x == 0 && tid < 256) {
        float s = 0.f, e = 0.f;
        for (int i = tid; i < BLOCKS; i += 256) {
            float2 p = partial[i];
            s += p.x; e += p.y;
        }
        #pragma unroll
        for (int off = 32; off; off >>= 1) {
            s += __shfl_down(s, off);
            e += __shfl_down(e, off);
        }
        if ((tid & 63) == 0) { shS[tid >> 6] = s; shE[tid >> 6] = e; }
    }
    __syncthreads();
    if (blockIdx.x == 0 && tid == 0) {
        const float inv = 1.0f / (float)CELLS;
        out[0] = (shS[0] + shS[1] + shS[2] + shS[3]) * inv;
        out[1] = (shE[0] + shE[1] + shE[2] + shE[3]) * inv;
    }

    unsigned vu[16];
    int bk[16];
    int zc = 0;
    #pragma unroll
    for (int i = 0; i < 16; i++) {
        float f = arr[tid + i * 1024];
        vu[i] = __float_as_uint(f);
        if (f > 0.0f) {
            int bb = (int)(f * 1024.0f);
            bk[i] = bb > 1023 ? 1023 : bb;
            atomicAdd(&hist[bk[i]], 1u);
        } else {
            bk[i] = 0;
            zc++;
        }
    }
    #pragma unroll
    for (int off = 32; off; off >>= 1) zc += __shfl_down(zc, off);
    if ((tid & 63) == 0 && zc) atomicAdd(&hist[0], (unsigned)zc);
    __syncthreads();

    if (tid < 64) {
        const int lane = tid;
        int m = attn[b * Lp + lane] + attn[b * Lp + 64 + lane];
        #pragma unroll
        for (int off = 32; off; off >>= 1) m += __shfl_down(m, off);
        m = __shfl(m, 0);
        int ml  = m - 2;
        int len = (int)((float)ml * 0.3f);
        len = len > 5 ? len : 5;
        int cap = ml * ml;
        len = len < cap ? len : cap;
        const unsigned k = (unsigned)len;

        unsigned h[16], s = 0u;
        #pragma unroll
        for (int j = 0; j < 16; j++) { h[j] = hist[16 * lane + j]; s += h[j]; }
        unsigned suf = s;
        #pragma unroll
        for (int off = 1; off < 64; off <<= 1) {
            unsigned t = __shfl_down(suf, off);
            if (lane + off < 64) suf += t;
        }
        unsigned run = suf - s;          // suffix just above this lane's bins
        int best = -1; unsigned snext = 0u;
        #pragma unroll
        for (int j = 15; j >= 0; j--) {
            unsigned nr = run + h[j];    // suffix at bin 16*lane+j
            if (best < 0 && nr >= k) { best = 16 * lane + j; snext = run; }
            run = nr;
        }
        unsigned long long msk = __ballot(best >= 0);
        int blane = 63 - __clzll(msk);
        if (lane == blane) { sh_B = (unsigned)best; sh_kk = k - snext; }
    }
    __syncthreads();

    const int B = (int)sh_B;
    const unsigned kk = sh_kk;

    #pragma unroll
    for (int i = 0; i < 16; i++) {
        if (bk[i] == B) {
            unsigned idx = atomicAdd(&sh_ccnt, 1u);
            if (idx < 2048u) cand[idx] = vu[i];
        }
    }
    __syncthreads();

    const unsigned C = sh_ccnt < 2048u ? sh_ccnt : 2048u;
    for (unsigned j = tid; j < C; j += 1024) {
        unsigned x = cand[j], g = 0u;
        for (unsigned i2 = 0; i2 < C; ++i2) g += (cand[i2] > x) ? 1u : 0u;
        if (g < kk) atomicMin(&sh_thr, x);
    }
    __syncthreads();

    const unsigned thr = sh_thr;
    #pragma unroll
    for (int i = 0; i < 16; i++)
        arr[tid + i * 1024] = (vu[i] >= thr) ? 1.0f : 0.0f;
}

extern "C" void kernel_launch(void* const* d_in, const int* in_sizes, int n_in,
                              void* d_out, int out_size, void* d_ws, size_t ws_size,
                              hipStream_t stream) {
    const float* table = (const float*)d_in[0];
    const int*   attn  = (const int*)d_in[1];
    const int*   labS  = (const int*)d_in[2];
    const int*   labE  = (const int*)d_in[3];
    const float* WS    = (const float*)d_in[4];
    const float* bS    = (const float*)d_in[5];
    const float* WE    = (const float*)d_in[6];
    const float* bE    = (const float*)d_in[7];
    float* out = (float*)d_out;
    float2* partial = (float2*)d_ws;

    logits_loss_kernel<<<BLOCKS, 256, 0, stream>>>(table, labS, labE, WS, bS, WE, bE,
                                                   out, partial);
    topk_predict_kernel<<<16, 1024, 0, stream>>>(attn, out, partial);
}